// Round 1
// baseline (1498.500 us; speedup 1.0000x reference)
//
#include <hip/hip_runtime.h>

#define TOTAL_B 65536
#define NKR 1024   // K*RANK = 64*16
#define ZD 128

// ---------------------------------------------------------------------------
// Kernel 1: w = z @ W^T + b + 1e-6   (fp32)
// z: [M, 128], W: [1024, 128] row-major, out: [M, 1024]
// Tile 128(M) x 128(N), K-chunks of 32, 256 threads, 8x8 micro-tile/thread.
// ---------------------------------------------------------------------------
__global__ __launch_bounds__(256) void gemm_zwt(
    const float* __restrict__ z, const float* __restrict__ W,
    const float* __restrict__ bias, float* __restrict__ out)
{
    __shared__ float zs[32][132];   // [k][m], pad 132 keeps 16B alignment
    __shared__ float ws[32][132];   // [k][n]

    const int tid = threadIdx.x;
    const int tx = tid & 15;        // n-direction
    const int ty = tid >> 4;        // m-direction
    const int m0 = blockIdx.y * 128;
    const int n0 = blockIdx.x * 128;

    float acc[8][8];
    #pragma unroll
    for (int i = 0; i < 8; ++i)
        #pragma unroll
        for (int j = 0; j < 8; ++j) acc[i][j] = 0.f;

    const int kq = (tid & 7) * 4;   // k offset within chunk (float4 granule)
    const int mr = tid >> 3;        // 0..31

    for (int kc = 0; kc < ZD; kc += 32) {
        #pragma unroll
        for (int p = 0; p < 4; ++p) {
            int ml = mr + p * 32;
            float4 v = *(const float4*)(z + (size_t)(m0 + ml) * ZD + kc + kq);
            zs[kq + 0][ml] = v.x; zs[kq + 1][ml] = v.y;
            zs[kq + 2][ml] = v.z; zs[kq + 3][ml] = v.w;
            float4 u = *(const float4*)(W + (size_t)(n0 + ml) * ZD + kc + kq);
            ws[kq + 0][ml] = u.x; ws[kq + 1][ml] = u.y;
            ws[kq + 2][ml] = u.z; ws[kq + 3][ml] = u.w;
        }
        __syncthreads();
        #pragma unroll 8
        for (int k = 0; k < 32; ++k) {
            float4 a0 = *(const float4*)&zs[k][ty * 8];
            float4 a1 = *(const float4*)&zs[k][ty * 8 + 4];
            float4 c0 = *(const float4*)&ws[k][tx * 8];
            float4 c1 = *(const float4*)&ws[k][tx * 8 + 4];
            float zr[8] = {a0.x, a0.y, a0.z, a0.w, a1.x, a1.y, a1.z, a1.w};
            float wr[8] = {c0.x, c0.y, c0.z, c0.w, c1.x, c1.y, c1.z, c1.w};
            #pragma unroll
            for (int i = 0; i < 8; ++i)
                #pragma unroll
                for (int j = 0; j < 8; ++j)
                    acc[i][j] = fmaf(zr[i], wr[j], acc[i][j]);
        }
        __syncthreads();
    }

    float bv[8];
    #pragma unroll
    for (int j = 0; j < 8; ++j) bv[j] = bias[n0 + tx * 8 + j] + 1e-6f;

    #pragma unroll
    for (int i = 0; i < 8; ++i) {
        size_t base = (size_t)(m0 + ty * 8 + i) * NKR + n0 + tx * 8;
        float4 o0, o1;
        o0.x = acc[i][0] + bv[0]; o0.y = acc[i][1] + bv[1];
        o0.z = acc[i][2] + bv[2]; o0.w = acc[i][3] + bv[3];
        o1.x = acc[i][4] + bv[4]; o1.y = acc[i][5] + bv[5];
        o1.z = acc[i][6] + bv[6]; o1.w = acc[i][7] + bv[7];
        *(float4*)(out + base) = o0;
        *(float4*)(out + base + 4) = o1;
    }
}

// ---------------------------------------------------------------------------
// Kernel 2: batched Householder QR (LAPACK sgeqr2 + sorg2r convention),
// one 64-lane wave per 64x16 matrix, lane = row. In-place on buf.
// ---------------------------------------------------------------------------
__device__ __forceinline__ float wsum(float v) {
    v += __shfl_xor(v, 1, 64);
    v += __shfl_xor(v, 2, 64);
    v += __shfl_xor(v, 4, 64);
    v += __shfl_xor(v, 8, 64);
    v += __shfl_xor(v, 16, 64);
    v += __shfl_xor(v, 32, 64);
    return v;
}

__global__ __launch_bounds__(256) void qr_batched(float* __restrict__ buf)
{
    const int tid = threadIdx.x;
    const int l = tid & 63;         // row
    const int wv = tid >> 6;        // wave id within block
    const int item = blockIdx.x * 4 + wv;
    __shared__ float tauS[4][16];

    float* p = buf + (size_t)item * NKR + l * 16;
    float a[16];
    #pragma unroll
    for (int c = 0; c < 16; c += 4) {
        float4 v = *(const float4*)(p + c);
        a[c] = v.x; a[c + 1] = v.y; a[c + 2] = v.z; a[c + 3] = v.w;
    }

    // ---- factorization: for j, generate v_j (stored into a[j]) and tau_j ----
    for (int j = 0; j < 16; ++j) {
        float ajv = 0.f;
        #pragma unroll
        for (int c = 0; c < 16; ++c) if (c == j) ajv = a[c];  // a[j], no dyn idx

        float xn2 = wsum((l > j) ? ajv * ajv : 0.f);
        float alpha = __shfl(ajv, j, 64);
        float tj, sc;
        if (xn2 == 0.f) { tj = 0.f; sc = 0.f; }
        else {
            float r = sqrtf(fmaf(alpha, alpha, xn2));
            float beta = (alpha >= 0.f) ? -r : r;   // LAPACK: beta = -sign(alpha)*r
            tj = (beta - alpha) / beta;
            sc = 1.f / (alpha - beta);
        }
        if (l == 0) tauS[wv][j] = tj;

        float vl = (l > j) ? ajv * sc : ((l == j) ? 1.f : 0.f);
        #pragma unroll
        for (int c = 0; c < 16; ++c) if (c == j) a[c] = vl;   // store v in-place

        // apply H_j = I - tau v v^T to trailing columns
        #pragma unroll
        for (int c = 0; c < 16; ++c) {
            if (c > j) {   // wave-uniform branch
                float d = wsum(vl * a[c]);
                a[c] = fmaf(-tj * d, vl, a[c]);
            }
        }
    }

    // ---- form Q = H_0 H_1 ... H_15 [I16; 0]  (apply in reverse order) ----
    float q[16];
    #pragma unroll
    for (int c = 0; c < 16; ++c) q[c] = (l == c) ? 1.f : 0.f;

    for (int j = 15; j >= 0; --j) {
        float vl = 0.f;
        #pragma unroll
        for (int c = 0; c < 16; ++c) if (c == j) vl = a[c];   // v_j (0 above, 1 at j)
        float tj = tauS[wv][j];
        #pragma unroll
        for (int c = 0; c < 16; ++c) {
            if (c >= j) {  // H_j only touches columns >= j (LAPACK sorg2r)
                float d = wsum(vl * q[c]);
                q[c] = fmaf(-tj * d, vl, q[c]);
            }
        }
    }

    #pragma unroll
    for (int c = 0; c < 16; c += 4) {
        float4 v = {q[c], q[c + 1], q[c + 2], q[c + 3]};
        *(float4*)(p + c) = v;
    }
}

extern "C" void kernel_launch(void* const* d_in, const int* in_sizes, int n_in,
                              void* d_out, int out_size, void* d_ws, size_t ws_size,
                              hipStream_t stream) {
    const float* z = (const float*)d_in[0];
    const float* W = (const float*)d_in[1];
    const float* b = (const float*)d_in[2];
    float* out = (float*)d_out;

    dim3 ggrid(NKR / 128, TOTAL_B / 128);   // (8, 512)
    hipLaunchKernelGGL(gemm_zwt, ggrid, dim3(256), 0, stream, z, W, b, out);
    hipLaunchKernelGGL(qr_batched, dim3(TOTAL_B / 4), dim3(256), 0, stream, out);
}

// Round 2
// 690.704 us; speedup vs baseline: 2.1695x; 2.1695x over previous
//
#include <hip/hip_runtime.h>

#define TOTAL_B 65536
#define NKR 1024   // K*RANK = 64*16
#define ZD 128

// ---------------------------------------------------------------------------
// Kernel 1: w = z @ W^T + b + 1e-6   (fp32)  -- unchanged from round 1
// ---------------------------------------------------------------------------
__global__ __launch_bounds__(256) void gemm_zwt(
    const float* __restrict__ z, const float* __restrict__ W,
    const float* __restrict__ bias, float* __restrict__ out)
{
    __shared__ float zs[32][132];
    __shared__ float ws[32][132];

    const int tid = threadIdx.x;
    const int tx = tid & 15;
    const int ty = tid >> 4;
    const int m0 = blockIdx.y * 128;
    const int n0 = blockIdx.x * 128;

    float acc[8][8];
    #pragma unroll
    for (int i = 0; i < 8; ++i)
        #pragma unroll
        for (int j = 0; j < 8; ++j) acc[i][j] = 0.f;

    const int kq = (tid & 7) * 4;
    const int mr = tid >> 3;

    for (int kc = 0; kc < ZD; kc += 32) {
        #pragma unroll
        for (int p = 0; p < 4; ++p) {
            int ml = mr + p * 32;
            float4 v = *(const float4*)(z + (size_t)(m0 + ml) * ZD + kc + kq);
            zs[kq + 0][ml] = v.x; zs[kq + 1][ml] = v.y;
            zs[kq + 2][ml] = v.z; zs[kq + 3][ml] = v.w;
            float4 u = *(const float4*)(W + (size_t)(n0 + ml) * ZD + kc + kq);
            ws[kq + 0][ml] = u.x; ws[kq + 1][ml] = u.y;
            ws[kq + 2][ml] = u.z; ws[kq + 3][ml] = u.w;
        }
        __syncthreads();
        #pragma unroll 8
        for (int k = 0; k < 32; ++k) {
            float4 a0 = *(const float4*)&zs[k][ty * 8];
            float4 a1 = *(const float4*)&zs[k][ty * 8 + 4];
            float4 c0 = *(const float4*)&ws[k][tx * 8];
            float4 c1 = *(const float4*)&ws[k][tx * 8 + 4];
            float zr[8] = {a0.x, a0.y, a0.z, a0.w, a1.x, a1.y, a1.z, a1.w};
            float wr[8] = {c0.x, c0.y, c0.z, c0.w, c1.x, c1.y, c1.z, c1.w};
            #pragma unroll
            for (int i = 0; i < 8; ++i)
                #pragma unroll
                for (int j = 0; j < 8; ++j)
                    acc[i][j] = fmaf(zr[i], wr[j], acc[i][j]);
        }
        __syncthreads();
    }

    float bv[8];
    #pragma unroll
    for (int j = 0; j < 8; ++j) bv[j] = bias[n0 + tx * 8 + j] + 1e-6f;

    #pragma unroll
    for (int i = 0; i < 8; ++i) {
        size_t base = (size_t)(m0 + ty * 8 + i) * NKR + n0 + tx * 8;
        float4 o0, o1;
        o0.x = acc[i][0] + bv[0]; o0.y = acc[i][1] + bv[1];
        o0.z = acc[i][2] + bv[2]; o0.w = acc[i][3] + bv[3];
        o1.x = acc[i][4] + bv[4]; o1.y = acc[i][5] + bv[5];
        o1.z = acc[i][6] + bv[6]; o1.w = acc[i][7] + bv[7];
        *(float4*)(out + base) = o0;
        *(float4*)(out + base + 4) = o1;
    }
}

// ---------------------------------------------------------------------------
// Kernel 2: batched Householder QR, 16 lanes per matrix (4 matrices/wave),
// lane q holds rows {q, q+16, q+32, q+48}. All reductions via DPP row_ror
// (VALU pipe) -- zero DS-pipe ops in the hot path.
// ---------------------------------------------------------------------------
template <int CTRL>
__device__ __forceinline__ float dpp_add(float v) {
    int x = __builtin_amdgcn_update_dpp(0, __float_as_int(v), CTRL, 0xF, 0xF, false);
    return v + __int_as_float(x);
}

// allreduce-sum over each aligned 16-lane group; exact same value on all 16
// lanes (pairwise tree combine -> FP-commutative identical results).
__device__ __forceinline__ float rsum16(float v) {
    v = dpp_add<0x128>(v);   // row_ror:8
    v = dpp_add<0x124>(v);   // row_ror:4
    v = dpp_add<0x122>(v);   // row_ror:2
    v = dpp_add<0x121>(v);   // row_ror:1
    return v;
}

__global__ __launch_bounds__(256) void qr_batched(float* __restrict__ buf)
{
    const int tid = threadIdx.x;
    const int lq = tid & 15;                         // lane within 16-group
    const int item = (blockIdx.x * 256 + tid) >> 4;  // one matrix per group

    float* p = buf + (size_t)item * NKR + lq * 16;   // row lq, col 0

    // load: a[c][i] = A[lq + 16*i][c]
    float a[16][4];
    #pragma unroll
    for (int i = 0; i < 4; ++i) {
        #pragma unroll
        for (int cc = 0; cc < 16; cc += 4) {
            float4 v = *(const float4*)(p + i * 256 + cc);
            a[cc + 0][i] = v.x; a[cc + 1][i] = v.y;
            a[cc + 2][i] = v.z; a[cc + 3][i] = v.w;
        }
    }

    float tau[16];

    // ---- factorization (LAPACK sgeqr2 / slarfg convention) ----
    #pragma unroll
    for (int j = 0; j < 16; ++j) {
        float x0 = a[j][0], x1 = a[j][1], x2 = a[j][2], x3 = a[j][3];
        // rows lq+16, lq+32, lq+48 are always > j (j < 16); row lq only if lq > j
        float x0m = (lq > j) ? x0 : 0.f;
        float pp = fmaf(x0m, x0m, fmaf(x1, x1, fmaf(x2, x2, x3 * x3)));
        float xn2   = rsum16(pp);
        float alpha = rsum16((lq == j) ? x0 : 0.f);

        float rr   = sqrtf(fmaf(alpha, alpha, xn2));
        float beta = (alpha >= 0.f) ? -rr : rr;
        float tj   = (beta - alpha) / beta;
        float sc   = 1.f / (alpha - beta);
        if (xn2 == 0.f) { tj = 0.f; sc = 0.f; }
        tau[j] = tj;

        float v0 = (lq == j) ? 1.f : ((lq > j) ? x0 * sc : 0.f);
        float v1 = x1 * sc, v2 = x2 * sc, v3 = x3 * sc;
        a[j][0] = v0; a[j][1] = v1; a[j][2] = v2; a[j][3] = v3;

        #pragma unroll
        for (int c = j + 1; c < 16; ++c) {
            float d = rsum16(fmaf(v0, a[c][0],
                        fmaf(v1, a[c][1],
                        fmaf(v2, a[c][2], v3 * a[c][3]))));
            float t = -tj * d;
            a[c][0] = fmaf(t, v0, a[c][0]);
            a[c][1] = fmaf(t, v1, a[c][1]);
            a[c][2] = fmaf(t, v2, a[c][2]);
            a[c][3] = fmaf(t, v3, a[c][3]);
        }
    }

    // ---- form Q (sorg2r): q_c = H_0 ... H_c e_c, 4 columns at a time ----
    #pragma unroll 1
    for (int c0 = 0; c0 < 16; c0 += 4) {
        float qq[4][4];
        #pragma unroll
        for (int k = 0; k < 4; ++k) {
            qq[k][0] = (lq == c0 + k) ? 1.f : 0.f;
            qq[k][1] = 0.f; qq[k][2] = 0.f; qq[k][3] = 0.f;
        }
        #pragma unroll
        for (int j = 15; j >= 0; --j) {
            if (j <= c0 + 3) {          // uniform; skips whole body when false
                float tj = tau[j];
                #pragma unroll
                for (int k = 0; k < 4; ++k) {
                    float d = rsum16(fmaf(a[j][0], qq[k][0],
                                fmaf(a[j][1], qq[k][1],
                                fmaf(a[j][2], qq[k][2], a[j][3] * qq[k][3]))));
                    float t = (j <= c0 + k) ? (-tj * d) : 0.f;
                    qq[k][0] = fmaf(t, a[j][0], qq[k][0]);
                    qq[k][1] = fmaf(t, a[j][1], qq[k][1]);
                    qq[k][2] = fmaf(t, a[j][2], qq[k][2]);
                    qq[k][3] = fmaf(t, a[j][3], qq[k][3]);
                }
            }
        }
        #pragma unroll
        for (int i = 0; i < 4; ++i) {
            float4 vv = {qq[0][i], qq[1][i], qq[2][i], qq[3][i]};
            *(float4*)(p + i * 256 + c0) = vv;
        }
    }
}

extern "C" void kernel_launch(void* const* d_in, const int* in_sizes, int n_in,
                              void* d_out, int out_size, void* d_ws, size_t ws_size,
                              hipStream_t stream) {
    const float* z = (const float*)d_in[0];
    const float* W = (const float*)d_in[1];
    const float* b = (const float*)d_in[2];
    float* out = (float*)d_out;

    dim3 ggrid(NKR / 128, TOTAL_B / 128);   // (8, 512)
    hipLaunchKernelGGL(gemm_zwt, ggrid, dim3(256), 0, stream, z, W, b, out);
    hipLaunchKernelGGL(qr_batched, dim3(TOTAL_B / 16), dim3(256), 0, stream, out);
}